// Round 2
// baseline (865.831 us; speedup 1.0000x reference)
//
#include <hip/hip_runtime.h>
#include <cstdint>
#include <cstddef>

typedef __attribute__((ext_vector_type(8))) short bf16x8;   // MFMA A/B frag (4 VGPRs)
typedef __attribute__((ext_vector_type(16))) float f32x16;  // MFMA C/D (16 VGPRs)

__device__ __forceinline__ unsigned short f2bf(float f) {   // fp32 -> bf16 RNE
    unsigned int u = __builtin_bit_cast(unsigned int, f);
    u += 0x7fffu + ((u >> 16) & 1u);
    return (unsigned short)(u >> 16);
}

// packed fp32x2 -> bf16x2 (HW v_cvt_pk_bf16_f32 on gfx950 when available)
__device__ __forceinline__ unsigned int pk2(float a, float b) {
#if __has_builtin(__builtin_amdgcn_cvt_pk_bf16_f32)
    auto r = __builtin_amdgcn_cvt_pk_bf16_f32(a, b);
    return __builtin_bit_cast(unsigned int, r);
#else
    return (unsigned int)f2bf(a) | ((unsigned int)f2bf(b) << 16);
#endif
}

template<int CTRL>
__device__ __forceinline__ float dpp_add(float v) {
    int t = __builtin_amdgcn_update_dpp(0, __builtin_bit_cast(int, v), CTRL, 0xf, 0xf, true);
    return v + __builtin_bit_cast(float, t);
}
// row_shr:1=0x111 :2=0x112 :4=0x114 :8=0x118 ; row_bcast15=0x142 ; row_ror:8=0x128

__device__ __forceinline__ float swz16_add(float v) {   // v += lane^16 partner
    int t = __builtin_amdgcn_ds_swizzle(__builtin_bit_cast(int, v), 0x401F);
    return v + __builtin_bit_cast(float, t);
}

__device__ __forceinline__ float fast_tanh(float x) {
    float e = __expf(2.0f * x);
    return 1.0f - 2.0f / (e + 1.0f);
}

// ---------------- prep: W1t[128][128], W2t[128][208] bf16, [n][k] ----------------
// W1t k-layout: k 0..99 = W1 rows (feat dims), k=100 = W1 row 100 (wei column),
// k=101 = b1 (paired with constant 1.0 on the A side) -> bias+wei term ride the
// MFMA K dimension; the fused kernel needs NO per-reg b1/w100 constants.
// W2t k-layout: k' 0..99 = W2 rows 0..99 (x), 100..103 = 0, 104..203 = W2 rows
// 100..199 (msg), 204..207 = 0  -> 13 frag-blocks of 16 with a clean hi-half split.
__global__ void prep_kernel(const float* __restrict__ W1, const float* __restrict__ b1,
                            const float* __restrict__ W2,
                            unsigned short* __restrict__ W1t, unsigned short* __restrict__ W2t)
{
    int idx = blockIdx.x * 256 + threadIdx.x;
    if (idx < 128 * 128) {
        int nn = idx >> 7, kk = idx & 127;
        unsigned short v = 0;
        if (nn < 100) {
            if (kk < 100)       v = f2bf(W1[kk * 100 + nn]);
            else if (kk == 100) v = f2bf(W1[100 * 100 + nn]);
            else if (kk == 101) v = f2bf(b1[nn]);
        }
        W1t[idx] = v;
    } else {
        int j = idx - 128 * 128;
        if (j < 128 * 208) {
            int nn = j / 208, kk = j - nn * 208;
            unsigned short v = 0;
            if (nn < 100) {
                if (kk < 100) v = f2bf(W2[kk * 100 + nn]);
                else if (kk >= 104 && kk < 204) v = f2bf(W2[(kk - 4) * 100 + nn]);
            }
            W2t[j] = v;
        }
    }
}

// ---------------- fused kernel: attention (32 nodes) + 2-layer MLP ----------------
// Occupancy is the governor: grid = 1563 equal-length blocks. At 7 blocks/CU the
// whole grid is co-resident (1792 slots) -> ONE scheduling round. That needs
// VGPR <= 512/7 = 73 (hence launch_bounds(256,7)) and LDS <= 23405 B (22592 B
// declared -> 23040 granule). Round-1 regression: 108 VGPRs -> 4 blocks/CU.
#define HP 104   // h_s / msg_s pitch (ushorts); 100 real + 4 zero pad

__global__ __launch_bounds__(256, 7) void fused_kernel(
    const int* __restrict__ nodes, const int* __restrict__ nei,
    const float* __restrict__ wei, const float* __restrict__ s_vec,
    const float* __restrict__ emb, const float* __restrict__ q1,
    const unsigned short* __restrict__ W1t, const unsigned short* __restrict__ W2t,
    const float* __restrict__ b2, float* __restrict__ out, int N)
{
    // h_s: neighbor rows [32][104] bf16 (attn) -> x rows (layer)
    // hst: hs=h*s, k-block-tiled [14 blocks][32 rows][8 ushorts] (conflict-free b128)
    //      block-12 hi-half row k carries {wei[k], 1.0, 0, 0} (bias ride-along)
    // msg_s: per-node attention messages, bf16, persists into the layer phase
    // part2: 4 slots (one per wave, full in-wave k-reduction done via butterfly)
    __shared__ __align__(16) unsigned short h_s[32 * HP];     // 6656 B
    __shared__ __align__(16) unsigned short hst[14 * 32 * 8]; // 7168 B
    __shared__ __align__(16) unsigned short msg_s[32 * HP];   // 6656 B
    __shared__ __align__(16) float part2[4 * 100];            // 1600 B
    __shared__ __align__(16) float spart[128];                // 512 B
    // total 22592 B -> 23040 alloc -> 7 blocks/CU

    const int tid  = threadIdx.x;
    const int lane = tid & 63;
    const int w    = tid >> 6;
    const int col  = lane & 31;
    const int hi   = lane >> 5;
    const int n    = w * 32 + col;          // layer-phase output column (>=100 masked)
    const int n0   = blockIdx.x * 32;       // this block's 32 consecutive nodes

    // persistent W1 fragments (A operand of the transposed score MFMA)
    bf16x8 Bf1[7];
    #pragma unroll
    for (int ks = 0; ks < 7; ++ks)
        Bf1[ks] = *(const bf16x8*)(W1t + n * 128 + ks * 16 + hi * 8);

    // q1 packed bf16 pairs: acc reg pair (2j,2j+1) maps to n-rows (nj, nj+1)
    unsigned int q1p[8];
    #pragma unroll
    for (int j = 0; j < 8; ++j) {
        int r  = 2 * j;
        int nj = w * 32 + (r & 3) + 8 * (r >> 2) + 4 * hi;
        float a = (nj     < 100) ? q1[nj]     : 0.0f;
        float b = (nj + 1 < 100) ? q1[nj + 1] : 0.0f;
        q1p[j] = pk2(a, b);
    }
    const bool nok = (n < 100);

    // zero pads once: hst block 13 (k' 104..111); h_s/msg_s d 100..103.
    // (hst block-12 hi-half is rewritten every iteration with the bias slots.)
    if (tid < 32) {
        *(uint4*)&hst[(13 * 32 + tid) * 8] = make_uint4(0, 0, 0, 0);
        *(uint2*)&h_s[tid * HP + 100]      = make_uint2(0, 0);
        *(uint2*)&msg_s[tid * HP + 100]    = make_uint2(0, 0);
    }

    const int gk = tid >> 3;   // staging row 0..31
    const int gj = tid & 7;    // staging float4-lane 0..7
    const bool t24 = (gj == 0);

    // T14 async-stage: emb rows (random gather = the real latency) live in VGPRs
    // one iteration ahead; nei index two ahead. s_vec is sequential/L3-resident,
    // loaded at stage time (dropping its prefetch saves 16 loop-carried VGPRs).
    float4 h0, h1, h2, h3;
    int   nidx_pf = 0;
    float wv = 0.0f;
    {
        int nid0 = nei[(size_t)n0 * 32 + gk];
        const float4* erow = (const float4*)(emb + (size_t)nid0 * 100);
        h0 = erow[gj];
        h1 = erow[gj + 8];
        h2 = erow[gj + 16];
        if (t24) h3 = erow[24];
        if (tid < 32) wv = wei[(size_t)n0 * 32 + tid];
        if (n0 + 1 < N) nidx_pf = nei[(size_t)(n0 + 1) * 32 + gk];
    }
    __syncthreads();

    for (int it = 0; it < 32; ++it) {
        const int node = n0 + it;
        if (node >= N) break;              // block-uniform

        // ---- stage: h_s (bf16) + hst (bf16, tiled, *s) + bias slots
        if (tid < 32)
            *(uint2*)&hst[(12 * 32 + tid) * 8 + 4] = make_uint2(pk2(wv, 1.0f), 0u);
        {
            const float4* srow = (const float4*)(s_vec + (size_t)node * 100);
            float4 sA = srow[gj], sB = srow[gj + 8], sC = srow[gj + 16];
            float4 sD;
            if (t24) sD = srow[24];
            #define ST_C4(c4, h4, s4) { \
                *(uint2*)&h_s[gk * HP + (c4) * 4] = \
                    make_uint2(pk2(h4.x, h4.y), pk2(h4.z, h4.w)); \
                *(uint2*)&hst[(((c4) >> 1) * 32 + gk) * 8 + ((c4) & 1) * 4] = \
                    make_uint2(pk2(h4.x * s4.x, h4.y * s4.y), pk2(h4.z * s4.z, h4.w * s4.w)); }
            ST_C4(gj,      h0, sA)
            ST_C4(gj + 8,  h1, sB)
            ST_C4(gj + 16, h2, sC)
            if (t24) { ST_C4(24, h3, sD) }
            #undef ST_C4
        }
        // ---- issue next node's emb gather now (consumed at top of it+1)
        if (it + 1 < 32 && node + 1 < N) {
            const float4* erow = (const float4*)(emb + (size_t)nidx_pf * 100);
            h0 = erow[gj];
            h1 = erow[gj + 8];
            h2 = erow[gj + 16];
            if (t24) h3 = erow[24];
            if (tid < 32) wv = wei[(size_t)(node + 1) * 32 + tid];
            if (it + 2 < 32 && node + 2 < N) nidx_pf = nei[(size_t)(node + 2) * 32 + gk];
        }
        __syncthreads();   // B1

        // ---- TRANSPOSED score matmul: C[row = n (per reg)][col = k (lane&31)]
        // bias + wei*W1row100 ride K slots 100/101 -> acc starts at zero.
        f32x16 acc;
        #pragma unroll
        for (int r = 0; r < 16; ++r) acc[r] = 0.0f;
        #pragma unroll
        for (int ks = 0; ks < 7; ++ks) {
            bf16x8 hfrag = *(const bf16x8*)&hst[((2 * ks + hi) * 32 + col) * 8];
            acc = __builtin_amdgcn_mfma_f32_32x32x16_bf16(Bf1[ks], hfrag, acc, 0, 0, 0);
        }

        // ---- epilogue: sum_n tanh(S)*q1, in-lane over 16 regs + one shfl
        float part = 0.0f;
        #pragma unroll
        for (int j = 0; j < 8; ++j) {
            float qa = __builtin_bit_cast(float, q1p[j] << 16);
            float qb = __builtin_bit_cast(float, q1p[j] & 0xffff0000u);
            part = fmaf(fast_tanh(acc[2 * j]),     qa, part);
            part = fmaf(fast_tanh(acc[2 * j + 1]), qb, part);
        }
        part += __shfl_xor(part, 32);
        if (lane < 32) spart[w * 32 + lane] = part;   // per-wave 32-n partial, k=lane
        __syncthreads();   // B2

        // ---- softmax over k, redundantly per wave (no extra barrier)
        float attk;
        {
            float s = spart[col] + spart[32 + col] + spart[64 + col] + spart[96 + col];
            float mx = s;
            #pragma unroll
            for (int off = 16; off; off >>= 1) mx = fmaxf(mx, __shfl_xor(mx, off));
            float e = __expf(s - mx);
            float den = e;
            #pragma unroll
            for (int off = 16; off; off >>= 1) den += __shfl_xor(den, off);
            float attv = e / den;
            attk = __shfl(attv, w * 8 + (lane >> 3));   // att for my k-row
        }

        // ---- msg partials: full in-wave k-butterfly -> ONE part2 slot per wave
        {
            const int oct  = lane & 7;
            const int krow = w * 8 + (lane >> 3);
            const float a  = attk;
            uint4 r1 = *(const uint4*)&h_s[krow * HP + oct * 8];
            const int oct2 = (oct < 5) ? oct : 4;   // clamped dup, masked at write
            uint4 r2 = *(const uint4*)&h_s[krow * HP + 64 + oct2 * 8];
            float m1[8], m2[8];
            #define UNP2(u, d0, d1) { d0 = __builtin_bit_cast(float, (u) << 16); \
                                      d1 = __builtin_bit_cast(float, (u) & 0xffff0000u); }
            { float t0,t1; UNP2(r1.x,t0,t1); m1[0]=a*t0; m1[1]=a*t1; }
            { float t0,t1; UNP2(r1.y,t0,t1); m1[2]=a*t0; m1[3]=a*t1; }
            { float t0,t1; UNP2(r1.z,t0,t1); m1[4]=a*t0; m1[5]=a*t1; }
            { float t0,t1; UNP2(r1.w,t0,t1); m1[6]=a*t0; m1[7]=a*t1; }
            { float t0,t1; UNP2(r2.x,t0,t1); m2[0]=a*t0; m2[1]=a*t1; }
            { float t0,t1; UNP2(r2.y,t0,t1); m2[2]=a*t0; m2[3]=a*t1; }
            { float t0,t1; UNP2(r2.z,t0,t1); m2[4]=a*t0; m2[5]=a*t1; }
            { float t0,t1; UNP2(r2.w,t0,t1); m2[6]=a*t0; m2[7]=a*t1; }
            #undef UNP2
            #pragma unroll
            for (int j = 0; j < 8; ++j) {   // k ^ 1 (row_ror:8 within 16-lane rows)
                m1[j] = dpp_add<0x128>(m1[j]);
                m2[j] = dpp_add<0x128>(m2[j]);
            }
            #pragma unroll
            for (int j = 0; j < 8; ++j) {   // k ^ 2 (ds_swizzle xor-16)
                m1[j] = swz16_add(m1[j]);
                m2[j] = swz16_add(m2[j]);
            }
            #pragma unroll
            for (int j = 0; j < 8; ++j) {   // k ^ 4 (cross 32-lane halves)
                m1[j] += __shfl_xor(m1[j], 32);
                m2[j] += __shfl_xor(m2[j], 32);
            }
            if ((lane >> 3) == 0) {         // lanes 0..7 hold the full 8-krow sums
                float* p = &part2[w * 100];
                *(float4*)&p[oct * 8]     = make_float4(m1[0], m1[1], m1[2], m1[3]);
                *(float4*)&p[oct * 8 + 4] = make_float4(m1[4], m1[5], m1[6], m1[7]);
                if (oct < 5) *(float4*)&p[64 + oct * 8]     = make_float4(m2[0], m2[1], m2[2], m2[3]);
                if (oct < 4) *(float4*)&p[64 + oct * 8 + 4] = make_float4(m2[4], m2[5], m2[6], m2[7]);
            }
        }
        __syncthreads();   // B4

        // ---- reduce 4 per-wave partials -> msg_s row (bf16), waves 0,1
        if (w < 2) {
            int d = w * 64 + lane;
            if (d < 100) {
                float s = part2[d] + part2[100 + d] + part2[200 + d] + part2[300 + d];
                msg_s[it * HP + d] = f2bf(s);
            }
        }
    }

    // ================= layer phase: x = relu([x,msg]@W2+b2) twice =================
    __syncthreads();   // all attn reads of h_s done; msg_s rows final after B_L1

    // x-gather (emb[nodes]) -> h_s region. W2 fragments are NOT kept persistent:
    // W2t (52 KB) is L2-hot across the whole grid, so each MFMA pass re-loads its
    // 13 fragments inline -- saves 52 VGPRs of layer-phase peak pressure.
    const float b2v = nok ? b2[n] : 0.0f;
    {
        int row = n0 + gk;
        int rc = row < N ? row : N - 1;
        const float4* xr = (const float4*)(emb + (size_t)nodes[rc] * 100);
        float4 x0 = xr[gj], x1 = xr[gj + 8], x2 = xr[gj + 16];
        float4 x3;
        if (t24) x3 = xr[24];
        *(uint2*)&h_s[gk * HP + gj * 4]        = make_uint2(pk2(x0.x, x0.y), pk2(x0.z, x0.w));
        *(uint2*)&h_s[gk * HP + (gj + 8) * 4]  = make_uint2(pk2(x1.x, x1.y), pk2(x1.z, x1.w));
        *(uint2*)&h_s[gk * HP + (gj + 16) * 4] = make_uint2(pk2(x2.x, x2.y), pk2(x2.z, x2.w));
        if (t24)
            *(uint2*)&h_s[gk * HP + 96]        = make_uint2(pk2(x3.x, x3.y), pk2(x3.z, x3.w));
    }
    __syncthreads();   // B_L1

    // A-frag address: k' blocks 0..12 -> h_s, 13..25 -> msg_s (ks=6 splits on hi)
    #define AFRAG(ks) (*(const bf16x8*)( \
        (ks) < 6  ? &h_s[col * HP + (ks) * 16 + hi * 8] : \
        (ks) == 6 ? (hi ? &msg_s[col * HP] : &h_s[col * HP + 96]) : \
                    &msg_s[col * HP + (ks) * 16 + hi * 8 - 104]))
    #define BFRAG(ks) (*(const bf16x8*)(W2t + n * 208 + (ks) * 16 + hi * 8))

    f32x16 acc;
    #pragma unroll
    for (int r = 0; r < 16; ++r) acc[r] = b2v;
    #pragma unroll
    for (int ks = 0; ks < 13; ++ks)
        acc = __builtin_amdgcn_mfma_f32_32x32x16_bf16(AFRAG(ks), BFRAG(ks), acc, 0, 0, 0);
    __syncthreads();   // B_L2: pass-1 reads done
    if (nok) {
        #pragma unroll
        for (int r = 0; r < 16; ++r) {
            int m = (r & 3) + 8 * (r >> 2) + 4 * hi;
            h_s[m * HP + n] = f2bf(fmaxf(acc[r], 0.0f));
        }
    }
    __syncthreads();   // B_L3

    f32x16 acc2;
    #pragma unroll
    for (int r = 0; r < 16; ++r) acc2[r] = b2v;
    #pragma unroll
    for (int ks = 0; ks < 13; ++ks)
        acc2 = __builtin_amdgcn_mfma_f32_32x32x16_bf16(AFRAG(ks), BFRAG(ks), acc2, 0, 0, 0);
    #undef AFRAG
    #undef BFRAG
    if (nok) {
        #pragma unroll
        for (int r = 0; r < 16; ++r) {
            int m = (r & 3) + 8 * (r >> 2) + 4 * hi;
            int row = n0 + m;
            if (row < N) out[(size_t)row * 100 + n] = fmaxf(acc2[r], 0.0f);
        }
    }
}

// ---------------- launch ----------------
extern "C" void kernel_launch(void* const* d_in, const int* in_sizes, int n_in,
                              void* d_out, int out_size, void* d_ws, size_t ws_size,
                              hipStream_t stream) {
    const int*   nodes = (const int*)d_in[0];
    const int*   nei   = (const int*)d_in[1];
    const float* wei   = (const float*)d_in[2];
    const float* s_vec = (const float*)d_in[3];
    const float* emb   = (const float*)d_in[4];
    const float* W1    = (const float*)d_in[5];
    const float* b1    = (const float*)d_in[6];
    const float* q1    = (const float*)d_in[7];
    const float* W2    = (const float*)d_in[8];
    const float* b2    = (const float*)d_in[9];
    float* out = (float*)d_out;
    const int N = in_sizes[0];

    unsigned short* W1t = (unsigned short*)d_ws;       // 128*128*2 = 32 KB
    unsigned short* W2t = W1t + 128 * 128;             // 128*208*2 = 52 KB

    prep_kernel<<<168, 256, 0, stream>>>(W1, b1, W2, W1t, W2t);
    const int gB = (N + 31) / 32;
    fused_kernel<<<gB, 256, 0, stream>>>(nodes, nei, wei, s_vec, emb, q1,
                                         W1t, W2t, b2, out, N);
}

// Round 3
// 672.744 us; speedup vs baseline: 1.2870x; 1.2870x over previous
//
#include <hip/hip_runtime.h>
#include <cstdint>
#include <cstddef>

typedef __attribute__((ext_vector_type(8))) short bf16x8;   // MFMA A/B frag (4 VGPRs)
typedef __attribute__((ext_vector_type(16))) float f32x16;  // MFMA C/D (16 VGPRs)

__device__ __forceinline__ unsigned short f2bf(float f) {   // fp32 -> bf16 RNE
    unsigned int u = __builtin_bit_cast(unsigned int, f);
    u += 0x7fffu + ((u >> 16) & 1u);
    return (unsigned short)(u >> 16);
}

// packed fp32x2 -> bf16x2 (HW v_cvt_pk_bf16_f32 on gfx950 when available)
__device__ __forceinline__ unsigned int pk2(float a, float b) {
#if __has_builtin(__builtin_amdgcn_cvt_pk_bf16_f32)
    auto r = __builtin_amdgcn_cvt_pk_bf16_f32(a, b);
    return __builtin_bit_cast(unsigned int, r);
#else
    return (unsigned int)f2bf(a) | ((unsigned int)f2bf(b) << 16);
#endif
}

template<int CTRL>
__device__ __forceinline__ float dpp_add(float v) {
    int t = __builtin_amdgcn_update_dpp(0, __builtin_bit_cast(int, v), CTRL, 0xf, 0xf, true);
    return v + __builtin_bit_cast(float, t);
}
template<int CTRL>
__device__ __forceinline__ float dpp_max(float v) {
    int t = __builtin_amdgcn_update_dpp(0, __builtin_bit_cast(int, v), CTRL, 0xf, 0xf, true);
    return fmaxf(v, __builtin_bit_cast(float, t));
}
// row_ror:N = 0x120|N (within-16 rotate == xor-reduce for commutative ops)

// gfx950 permlane swaps: {a,b} = swap(v,v) leaves a=v_partner-half dup, b=v_own-half
// dup -> a OP b == v OP v[lane^16 / lane^32] broadcast to ALL lanes. VALU-pipe
// (replaces ds_swizzle/ds_bpermute, ~120cy DS latency each -> ~4cy).
__device__ __forceinline__ float pl16_add(float v) {
    float a = v, b = v;
    asm("v_permlane16_swap_b32 %0, %1" : "+v"(a), "+v"(b));
    return a + b;
}
__device__ __forceinline__ float pl16_max(float v) {
    float a = v, b = v;
    asm("v_permlane16_swap_b32 %0, %1" : "+v"(a), "+v"(b));
    return fmaxf(a, b);
}
__device__ __forceinline__ float pl32_add(float v) {
    float a = v, b = v;
    asm("v_permlane32_swap_b32 %0, %1" : "+v"(a), "+v"(b));
    return a + b;
}

__device__ __forceinline__ float fast_tanh(float x) {
    float e = __expf(2.0f * x);
    return 1.0f - 2.0f / (e + 1.0f);
}

// ---------------- prep: W1t[128][128], W2t[128][208] bf16, [n][k] ----------------
// W1t k-layout: k 0..99 = W1 rows (feat dims), k=100 = W1 row 100 (wei column),
// k=101 = b1 (paired with constant 1.0 on the A side) -> bias+wei term ride the
// MFMA K dimension; the fused kernel needs NO per-reg b1/w100 constants.
// W2t k-layout: k' 0..99 = W2 rows 0..99 (x), 100..103 = 0, 104..203 = W2 rows
// 100..199 (msg), 204..207 = 0  -> 13 frag-blocks of 16 with a clean hi-half split.
__global__ void prep_kernel(const float* __restrict__ W1, const float* __restrict__ b1,
                            const float* __restrict__ W2,
                            unsigned short* __restrict__ W1t, unsigned short* __restrict__ W2t)
{
    int idx = blockIdx.x * 256 + threadIdx.x;
    if (idx < 128 * 128) {
        int nn = idx >> 7, kk = idx & 127;
        unsigned short v = 0;
        if (nn < 100) {
            if (kk < 100)       v = f2bf(W1[kk * 100 + nn]);
            else if (kk == 100) v = f2bf(W1[100 * 100 + nn]);
            else if (kk == 101) v = f2bf(b1[nn]);
        }
        W1t[idx] = v;
    } else {
        int j = idx - 128 * 128;
        if (j < 128 * 208) {
            int nn = j / 208, kk = j - nn * 208;
            unsigned short v = 0;
            if (nn < 100) {
                if (kk < 100) v = f2bf(W2[kk * 100 + nn]);
                else if (kk >= 104 && kk < 204) v = f2bf(W2[(kk - 4) * 100 + nn]);
            }
            W2t[j] = v;
        }
    }
}

// ---------------- fused kernel: attention (32 nodes) + 2-layer MLP ----------------
// Occupancy governor: grid = 1563 equal-length blocks; 7 blocks/CU (1792 slots)
// makes the whole grid co-resident -> ONE scheduling round. LDS 22592 B fits
// (<=23405). VGPR must land <=~73 NATURALLY -- a launch_bounds cap triggers
// spill collapse (round 2: cap -> VGPR 36, WRITE_SIZE 20->210 MB, dur +49%).
// Register plan: W1 A-frags + q1 consts are per-iteration L1/L2 re-loads (asm
// pointer-clobbers defeat LICM) living in windows where the h-prefetch is dead.
#define HP 104   // h_s / msg_s pitch (ushorts); 100 real + 4 zero pad

__global__ __launch_bounds__(256) void fused_kernel(
    const int* __restrict__ nodes, const int* __restrict__ nei,
    const float* __restrict__ wei, const float* __restrict__ s_vec,
    const float* __restrict__ emb, const float* __restrict__ q1,
    const unsigned short* __restrict__ W1t, const unsigned short* __restrict__ W2t,
    const float* __restrict__ b2, float* __restrict__ out, int N)
{
    __shared__ __align__(16) unsigned short h_s[32 * HP];     // 6656 B
    __shared__ __align__(16) unsigned short hst[14 * 32 * 8]; // 7168 B
    __shared__ __align__(16) unsigned short msg_s[32 * HP];   // 6656 B
    __shared__ __align__(16) float part2[4 * 100];            // 1600 B
    __shared__ __align__(16) float spart[128];                // 512 B
    // total 22592 B -> 7 blocks/CU by LDS

    const int tid  = threadIdx.x;
    const int lane = tid & 63;
    const int w    = tid >> 6;
    const int col  = lane & 31;
    const int hi   = lane >> 5;
    const int n    = w * 32 + col;          // layer-phase output column (>=100 masked)
    const int n0   = blockIdx.x * 32;       // this block's 32 consecutive nodes
    const bool nok = (n < 100);

    // per-iteration re-fetched constant pointers (asm-clobbered in the loop)
    const unsigned short* w1p  = W1t + n * 128 + hi * 8;   // A-frag base (this thread)
    const float*          q1p4 = q1 + w * 32 + 4 * hi;     // epilogue q1 float4 base

    // zero pads once: hst block 13 (k' 104..111); h_s/msg_s d 100..103.
    // (hst block-12 hi-half is rewritten every iteration with the bias slots.)
    if (tid < 32) {
        *(uint4*)&hst[(13 * 32 + tid) * 8] = make_uint4(0, 0, 0, 0);
        *(uint2*)&h_s[tid * HP + 100]      = make_uint2(0, 0);
        *(uint2*)&msg_s[tid * HP + 100]    = make_uint2(0, 0);
    }

    const int gk = tid >> 3;   // staging row 0..31
    const int gj = tid & 7;    // staging float4-lane 0..7
    const bool t24 = (gj == 0);

    // emb-row prefetch (the random gather = the real latency): one node ahead,
    // nei index two ahead. s_vec is sequential, loaded at stage time.
    float4 h0, h1, h2, h3;
    int   nidx_pf = 0;
    float wv = 0.0f;
    {
        int nid0 = nei[(size_t)n0 * 32 + gk];
        const float4* erow = (const float4*)(emb + (size_t)nid0 * 100);
        h0 = erow[gj];
        h1 = erow[gj + 8];
        h2 = erow[gj + 16];
        if (t24) h3 = erow[24];
        if (tid < 32) wv = wei[(size_t)n0 * 32 + tid];
        if (n0 + 1 < N) nidx_pf = nei[(size_t)(n0 + 1) * 32 + gk];
    }
    __syncthreads();

    for (int it = 0; it < 32; ++it) {
        const int node = n0 + it;
        if (node >= N) break;              // block-uniform

        // ---- stage: h_s (bf16) + hst (bf16, tiled, *s) + bias slots
        if (tid < 32)
            *(uint2*)&hst[(12 * 32 + tid) * 8 + 4] = make_uint2(pk2(wv, 1.0f), 0u);
        {
            const float4* srow = (const float4*)(s_vec + (size_t)node * 100);
            float4 sA = srow[gj], sB = srow[gj + 8], sC = srow[gj + 16];
            float4 sD;
            if (t24) sD = srow[24];
            #define ST_C4(c4, h4, s4) { \
                *(uint2*)&h_s[gk * HP + (c4) * 4] = \
                    make_uint2(pk2(h4.x, h4.y), pk2(h4.z, h4.w)); \
                *(uint2*)&hst[(((c4) >> 1) * 32 + gk) * 8 + ((c4) & 1) * 4] = \
                    make_uint2(pk2(h4.x * s4.x, h4.y * s4.y), pk2(h4.z * s4.z, h4.w * s4.w)); }
            ST_C4(gj,      h0, sA)
            ST_C4(gj + 8,  h1, sB)
            ST_C4(gj + 16, h2, sC)
            if (t24) { ST_C4(24, h3, sD) }
            #undef ST_C4
        }
        // ---- W1 A-frags: re-fetched from L2-hot W1t every iteration. The asm
        // clobber defeats LICM so they never become 28 PERSISTENT regs; h0..h3
        // are dead right here, so the 28 transients reuse that space. Drained at
        // B1 (~L2 latency, mostly covered by the pack above).
        asm volatile("" : "+v"(w1p));
        bf16x8 af[7];
        #pragma unroll
        for (int ks = 0; ks < 7; ++ks) af[ks] = *(const bf16x8*)(w1p + ks * 16);
        __syncthreads();   // B1

        // ---- TRANSPOSED score matmul: C[row = n (per reg)][col = k (lane&31)]
        // bias + wei*W1row100 ride K slots 100/101 -> acc starts at zero.
        f32x16 acc;
        #pragma unroll
        for (int r = 0; r < 16; ++r) acc[r] = 0.0f;
        #pragma unroll
        for (int ks = 0; ks < 7; ++ks) {
            bf16x8 hfrag = *(const bf16x8*)&hst[((2 * ks + hi) * 32 + col) * 8];
            acc = __builtin_amdgcn_mfma_f32_32x32x16_bf16(af[ks], hfrag, acc, 0, 0, 0);
        }

        // ---- epilogue: sum_n tanh(S)*q1. q1 re-loaded per iteration (L1-hot,
        // clobbered pointer) -> no persistent q1 regs; in-lane fma over 16 regs
        // + one permlane32 combine.
        asm volatile("" : "+v"(q1p4));
        float4 jq[4];
        #pragma unroll
        for (int m = 0; m < 4; ++m) {
            int nb = w * 32 + 4 * hi + 8 * m;
            jq[m] = (nb < 100) ? *(const float4*)(q1p4 + 8 * m)
                               : make_float4(0.f, 0.f, 0.f, 0.f);
        }
        float part = 0.0f;
        #pragma unroll
        for (int m = 0; m < 4; ++m) {
            part = fmaf(fast_tanh(acc[4 * m + 0]), jq[m].x, part);
            part = fmaf(fast_tanh(acc[4 * m + 1]), jq[m].y, part);
            part = fmaf(fast_tanh(acc[4 * m + 2]), jq[m].z, part);
            part = fmaf(fast_tanh(acc[4 * m + 3]), jq[m].w, part);
        }
        part = pl32_add(part);
        if (lane < 32) spart[w * 32 + lane] = part;   // per-wave 32-n partial, k=lane
        __syncthreads();   // B2

        // ---- issue next node's emb gather HERE: every barrier drains vmcnt(0),
        // so post-B2 issue gets softmax+butterfly as latency cover and drains
        // cleanly at B4 (pre-B1 issue would stall B1 on the full gather).
        if (it + 1 < 32 && node + 1 < N) {
            const float4* erow = (const float4*)(emb + (size_t)nidx_pf * 100);
            h0 = erow[gj];
            h1 = erow[gj + 8];
            h2 = erow[gj + 16];
            if (t24) h3 = erow[24];
            if (tid < 32) wv = wei[(size_t)(node + 1) * 32 + tid];
            if (it + 2 < 32 && node + 2 < N) nidx_pf = nei[(size_t)(node + 2) * 32 + gk];
        }

        // ---- softmax over k, redundantly per wave. All cross-lane via DPP ror
        // (within-16) + permlane16 (row-pair) -> VALU pipe, no DS latency chain.
        float attk;
        {
            float s = spart[col] + spart[32 + col] + spart[64 + col] + spart[96 + col];
            float mx = s;
            mx = dpp_max<0x121>(mx);
            mx = dpp_max<0x122>(mx);
            mx = dpp_max<0x124>(mx);
            mx = dpp_max<0x128>(mx);
            mx = pl16_max(mx);
            float e = __expf(s - mx);
            float den = e;
            den = dpp_add<0x121>(den);
            den = dpp_add<0x122>(den);
            den = dpp_add<0x124>(den);
            den = dpp_add<0x128>(den);
            den = pl16_add(den);
            float attv = e / den;
            attk = __shfl(attv, w * 8 + (lane >> 3));   // att for my k-row
        }

        // ---- msg partials: full in-wave k-butterfly (k^1 dpp ror:8, k^2
        // permlane16, k^4 permlane32) -> ONE part2 slot per wave, zero DS ops.
        {
            const int oct  = lane & 7;
            const int krow = w * 8 + (lane >> 3);
            const float a  = attk;
            uint4 r1 = *(const uint4*)&h_s[krow * HP + oct * 8];
            const int oct2 = (oct < 5) ? oct : 4;   // clamped dup, masked at write
            uint4 r2 = *(const uint4*)&h_s[krow * HP + 64 + oct2 * 8];
            float m1[8], m2[8];
            #define UNP2(u, d0, d1) { d0 = __builtin_bit_cast(float, (u) << 16); \
                                      d1 = __builtin_bit_cast(float, (u) & 0xffff0000u); }
            { float t0,t1; UNP2(r1.x,t0,t1); m1[0]=a*t0; m1[1]=a*t1; }
            { float t0,t1; UNP2(r1.y,t0,t1); m1[2]=a*t0; m1[3]=a*t1; }
            { float t0,t1; UNP2(r1.z,t0,t1); m1[4]=a*t0; m1[5]=a*t1; }
            { float t0,t1; UNP2(r1.w,t0,t1); m1[6]=a*t0; m1[7]=a*t1; }
            { float t0,t1; UNP2(r2.x,t0,t1); m2[0]=a*t0; m2[1]=a*t1; }
            { float t0,t1; UNP2(r2.y,t0,t1); m2[2]=a*t0; m2[3]=a*t1; }
            { float t0,t1; UNP2(r2.z,t0,t1); m2[4]=a*t0; m2[5]=a*t1; }
            { float t0,t1; UNP2(r2.w,t0,t1); m2[6]=a*t0; m2[7]=a*t1; }
            #undef UNP2
            #pragma unroll
            for (int j = 0; j < 8; ++j) {   // k ^ 1 (ror:8 == xor:8 within 16)
                m1[j] = dpp_add<0x128>(m1[j]);
                m2[j] = dpp_add<0x128>(m2[j]);
            }
            #pragma unroll
            for (int j = 0; j < 8; ++j) {   // k ^ 2
                m1[j] = pl16_add(m1[j]);
                m2[j] = pl16_add(m2[j]);
            }
            #pragma unroll
            for (int j = 0; j < 8; ++j) {   // k ^ 4
                m1[j] = pl32_add(m1[j]);
                m2[j] = pl32_add(m2[j]);
            }
            if ((lane >> 3) == 0) {         // all lanes hold full sums; lanes 0..7 write
                float* p = &part2[w * 100];
                *(float4*)&p[oct * 8]     = make_float4(m1[0], m1[1], m1[2], m1[3]);
                *(float4*)&p[oct * 8 + 4] = make_float4(m1[4], m1[5], m1[6], m1[7]);
                if (oct < 5) *(float4*)&p[64 + oct * 8]     = make_float4(m2[0], m2[1], m2[2], m2[3]);
                if (oct < 4) *(float4*)&p[64 + oct * 8 + 4] = make_float4(m2[4], m2[5], m2[6], m2[7]);
            }
        }
        __syncthreads();   // B4 (also drains the post-B2 emb prefetch)

        // ---- reduce 4 per-wave partials -> msg_s row (bf16), waves 0,1
        if (w < 2) {
            int d = w * 64 + lane;
            if (d < 100) {
                float s = part2[d] + part2[100 + d] + part2[200 + d] + part2[300 + d];
                msg_s[it * HP + d] = f2bf(s);
            }
        }
    }

    // ================= layer phase: x = relu([x,msg]@W2+b2) twice =================
    __syncthreads();   // all attn reads of h_s done; msg_s rows final after B_L1

    // x-gather (emb[nodes]) -> h_s region. W2 fragments stream from L2 inside a
    // partially-unrolled loop (unroll 2 keeps ~2 frags in flight, bounding the
    // layer-phase register peak; a fully-unrolled loop batches all 13 = 104 regs).
    const float b2v = nok ? b2[n] : 0.0f;
    {
        int row = n0 + gk;
        int rc = row < N ? row : N - 1;
        const float4* xr = (const float4*)(emb + (size_t)nodes[rc] * 100);
        float4 x0 = xr[gj], x1 = xr[gj + 8], x2 = xr[gj + 16];
        float4 x3;
        if (t24) x3 = xr[24];
        *(uint2*)&h_s[gk * HP + gj * 4]        = make_uint2(pk2(x0.x, x0.y), pk2(x0.z, x0.w));
        *(uint2*)&h_s[gk * HP + (gj + 8) * 4]  = make_uint2(pk2(x1.x, x1.y), pk2(x1.z, x1.w));
        *(uint2*)&h_s[gk * HP + (gj + 16) * 4] = make_uint2(pk2(x2.x, x2.y), pk2(x2.z, x2.w));
        if (t24)
            *(uint2*)&h_s[gk * HP + 96]        = make_uint2(pk2(x3.x, x3.y), pk2(x3.z, x3.w));
    }
    __syncthreads();   // B_L1

    // A-frag address: k' blocks 0..12 -> h_s, 13..25 -> msg_s (ks=6 splits on hi)
    #define AFRAG(ks) (*(const bf16x8*)( \
        (ks) < 6  ? &h_s[col * HP + (ks) * 16 + hi * 8] : \
        (ks) == 6 ? (hi ? &msg_s[col * HP] : &h_s[col * HP + 96]) : \
                    &msg_s[col * HP + (ks) * 16 + hi * 8 - 104]))
    #define BFRAG(ks) (*(const bf16x8*)(W2t + n * 208 + (ks) * 16 + hi * 8))

    f32x16 acc;
    #pragma unroll
    for (int r = 0; r < 16; ++r) acc[r] = b2v;
    #pragma unroll 2
    for (int ks = 0; ks < 13; ++ks)
        acc = __builtin_amdgcn_mfma_f32_32x32x16_bf16(AFRAG(ks), BFRAG(ks), acc, 0, 0, 0);
    __syncthreads();   // B_L2: pass-1 reads done
    if (nok) {
        #pragma unroll
        for (int r = 0; r < 16; ++r) {
            int m = (r & 3) + 8 * (r >> 2) + 4 * hi;
            h_s[m * HP + n] = f2bf(fmaxf(acc[r], 0.0f));
        }
    }
    __syncthreads();   // B_L3

    f32x16 acc2;
    #pragma unroll
    for (int r = 0; r < 16; ++r) acc2[r] = b2v;
    #pragma unroll 2
    for (int ks = 0; ks < 13; ++ks)
        acc2 = __builtin_amdgcn_mfma_f32_32x32x16_bf16(AFRAG(ks), BFRAG(ks), acc2, 0, 0, 0);
    #undef AFRAG
    #undef BFRAG
    if (nok) {
        #pragma unroll
        for (int r = 0; r < 16; ++r) {
            int m = (r & 3) + 8 * (r >> 2) + 4 * hi;
            int row = n0 + m;
            if (row < N) out[(size_t)row * 100 + n] = fmaxf(acc2[r], 0.0f);
        }
    }
}

// ---------------- launch ----------------
extern "C" void kernel_launch(void* const* d_in, const int* in_sizes, int n_in,
                              void* d_out, int out_size, void* d_ws, size_t ws_size,
                              hipStream_t stream) {
    const int*   nodes = (const int*)d_in[0];
    const int*   nei   = (const int*)d_in[1];
    const float* wei   = (const float*)d_in[2];
    const float* s_vec = (const float*)d_in[3];
    const float* emb   = (const float*)d_in[4];
    const float* W1    = (const float*)d_in[5];
    const float* b1    = (const float*)d_in[6];
    const float* q1    = (const float*)d_in[7];
    const float* W2    = (const float*)d_in[8];
    const float* b2    = (const float*)d_in[9];
    float* out = (float*)d_out;
    const int N = in_sizes[0];

    unsigned short* W1t = (unsigned short*)d_ws;       // 128*128*2 = 32 KB
    unsigned short* W2t = W1t + 128 * 128;             // 128*208*2 = 52 KB

    prep_kernel<<<168, 256, 0, stream>>>(W1, b1, W2, W1t, W2t);
    const int gB = (N + 31) / 32;
    fused_kernel<<<gB, 256, 0, stream>>>(nodes, nei, wei, s_vec, emb, q1,
                                         W1t, W2t, b2, out, N);
}

// Round 5
// 588.840 us; speedup vs baseline: 1.4704x; 1.1425x over previous
//
#include <hip/hip_runtime.h>
#include <cstdint>
#include <cstddef>

typedef __attribute__((ext_vector_type(8))) short bf16x8;   // MFMA A/B frag (4 VGPRs)
typedef __attribute__((ext_vector_type(16))) float f32x16;  // MFMA C/D (16 VGPRs)

__device__ __forceinline__ unsigned short f2bf(float f) {   // fp32 -> bf16 RNE
    unsigned int u = __builtin_bit_cast(unsigned int, f);
    u += 0x7fffu + ((u >> 16) & 1u);
    return (unsigned short)(u >> 16);
}

// packed fp32x2 -> bf16x2, MANUAL RNE. Round 4 used raw v_cvt_pk_bf16_f32 and
// FAILED accuracy (absmax 2.3e-3 vs 8.9e-4): the HW pack is not RNE-equivalent,
// and its biased error accumulates linearly through 100-200-term MFMA dots.
// Do NOT switch this back to the HW instruction without an accuracy A/B.
__device__ __forceinline__ unsigned int pk2(float a, float b) {
    return (unsigned int)f2bf(a) | ((unsigned int)f2bf(b) << 16);
}

template<int CTRL>
__device__ __forceinline__ float dpp_add(float v) {
    int t = __builtin_amdgcn_update_dpp(0, __builtin_bit_cast(int, v), CTRL, 0xf, 0xf, true);
    return v + __builtin_bit_cast(float, t);
}
template<int CTRL>
__device__ __forceinline__ float dpp_max(float v) {
    int t = __builtin_amdgcn_update_dpp(0, __builtin_bit_cast(int, v), CTRL, 0xf, 0xf, true);
    return fmaxf(v, __builtin_bit_cast(float, t));
}
// row_ror:N = 0x120|N (within-16 rotate == xor-reduce for commutative ops)

__device__ __forceinline__ float pl16_add(float v) {   // v + v[lane^16], all lanes
    float a = v, b = v;
    asm("v_permlane16_swap_b32 %0, %1" : "+v"(a), "+v"(b));
    return a + b;
}
__device__ __forceinline__ float pl16_max(float v) {
    float a = v, b = v;
    asm("v_permlane16_swap_b32 %0, %1" : "+v"(a), "+v"(b));
    return fmaxf(a, b);
}
__device__ __forceinline__ float pl32_add(float v) {   // v + v[lane^32], all lanes
    float a = v, b = v;
    asm("v_permlane32_swap_b32 %0, %1" : "+v"(a), "+v"(b));
    return a + b;
}

// tanh(x) = 1 - 2/(e^{2x}+1) via v_rcp (1 inst, ~1e-7 rel err -> negligible).
__device__ __forceinline__ float fast_tanh(float x) {
    float e = __expf(2.0f * x);
    float r = __builtin_amdgcn_rcpf(e + 1.0f);
    return fmaf(-2.0f, r, 1.0f);
}

// hst bank swizzle: uniform at EVERY hst access site (stage, bias, init, MFMA,
// butterfly). Without it: MFMA HF reads are 4-way conflicted (bank = 4*col%32),
// butterfly reads 8-way (bank oct-invariant). With k ^= ((b&3)^((k>>3)&3))<<1:
// MFMA 1-way, butterfly 2-way (free, m136), stage writes 1-way. Bijective within
// each block's 32 k-rows; preserves 16B alignment (index scaled by 8 ushorts).
__device__ __forceinline__ int hidx(int b, int k) {
    return (b * 32 + (k ^ ((((b) & 3) ^ ((k >> 3) & 3)) << 1))) * 8;
}

// -------- prep: W1t[128][128], W2t[128][208] bf16 [n][k]; q1pad[128] f32 --------
// W1t k-layout: k 0..99 = W1 rows, k=100 = W1 row 100 (wei), k=101 = b1 (paired
// with 1.0 on the A side) -> bias+wei ride the MFMA K dimension.
// W2t k-layout: k' 0..99 = W2 rows 0..99 (x), 100..103 = 0, 104..203 = W2 rows
// 100..199 (msg), 204..207 = 0.
// q1pad: q1 zero-padded to 128 so the epilogue loads need no bounds guard.
__global__ void prep_kernel(const float* __restrict__ W1, const float* __restrict__ b1,
                            const float* __restrict__ W2, const float* __restrict__ q1,
                            unsigned short* __restrict__ W1t, unsigned short* __restrict__ W2t,
                            float* __restrict__ q1pad)
{
    int idx = blockIdx.x * 256 + threadIdx.x;
    if (idx < 128) q1pad[idx] = (idx < 100) ? q1[idx] : 0.0f;
    if (idx < 128 * 128) {
        int nn = idx >> 7, kk = idx & 127;
        unsigned short v = 0;
        if (nn < 100) {
            if (kk < 100)       v = f2bf(W1[kk * 100 + nn]);
            else if (kk == 100) v = f2bf(W1[100 * 100 + nn]);
            else if (kk == 101) v = f2bf(b1[nn]);
        }
        W1t[idx] = v;
    } else {
        int j = idx - 128 * 128;
        if (j < 128 * 208) {
            int nn = j / 208, kk = j - nn * 208;
            unsigned short v = 0;
            if (nn < 100) {
                if (kk < 100) v = f2bf(W2[kk * 100 + nn]);
                else if (kk >= 104 && kk < 204) v = f2bf(W2[(kk - 4) * 100 + nn]);
            }
            W2t[j] = v;
        }
    }
}

// ---------------- fused kernel: attention (32 nodes) + 2-layer MLP ----------------
// VGPR <=64 is THE occupancy target (8 waves/SIMD under both granularity models
// -> 2048 block-slots >= 1563 grid -> single scheduling round). Must be reached
// NATURALLY: launch_bounds caps collapse the allocator (round 2: cap -> spill,
// WRITE_SIZE 20->210 MB). Measures: no emb prefetch regs (TLP covers at high
// occupancy), af split 4+3 behind a sched_barrier (peak 16 not 28 in flight),
// sequential m1/m2 butterfly, h_s staging deleted (msg = butterfly(hst)/s_vec).
#define HP 104   // msg_s / x_s pitch (ushorts); 100 real + 4 zero pad

__global__ __launch_bounds__(256) void fused_kernel(
    const int* __restrict__ nodes, const int* __restrict__ nei,
    const float* __restrict__ wei, const float* __restrict__ s_vec,
    const float* __restrict__ emb,
    const unsigned short* __restrict__ W1t, const unsigned short* __restrict__ W2t,
    const float* __restrict__ q1pad,
    const float* __restrict__ b2, float* __restrict__ out, int N)
{
    // hst: hs=h*s, k-block-tiled [14 blocks][32 k-rows][8 ushorts], bank-swizzled
    //      via hidx(). Block-12 hi-half row k = {wei[k], 1.0, 0, 0}; block 13 = 0.
    //      Serves the score MFMA AND the msg butterfly (msg recovers h via /s_vec
    //      at the reduce). Reused as x rows [32][HP] (unswizzled) in layer phase.
    // msg_s: per-node attention messages, bf16, persists into the layer phase
    __shared__ __align__(16) unsigned short hst[14 * 32 * 8]; // 7168 B
    __shared__ __align__(16) unsigned short msg_s[32 * HP];   // 6656 B
    __shared__ __align__(16) float part2[4 * 100];            // 1600 B
    __shared__ __align__(16) float spart[128];                // 512 B
    // total 15936 B -- LDS is not the occupancy governor

    const int tid  = threadIdx.x;
    const int lane = tid & 63;
    const int w    = tid >> 6;
    const int col  = lane & 31;
    const int hi   = lane >> 5;
    const int n    = w * 32 + col;          // layer-phase output column (>=100 masked)
    const int n0   = blockIdx.x * 32;       // this block's 32 consecutive nodes
    const bool nok = (n < 100);

    // per-iteration re-fetched offsets (asm-clobbered in the loop defeats LICM
    // so W1/q1 fragments never become persistent registers)
    int w1off = n * 128 + hi * 8;
    int q1off = w * 32 + 4 * hi;

    // zero hst block 13 (k' 104..111) + msg_s pad once
    if (tid < 32) {
        *(uint4*)&hst[hidx(13, tid)]    = make_uint4(0, 0, 0, 0);
        *(uint2*)&msg_s[tid * HP + 100] = make_uint2(0, 0);
    }

    const int gk = tid >> 3;   // staging row 0..31
    const int gj = tid & 7;    // staging float4-lane 0..7
    const bool t24 = (gj == 0);

    // only the nei index + wei value are prefetched one ahead (2 regs); the emb
    // rows themselves are loaded at stage time -- at 8 waves/SIMD TLP hides the
    // gather latency (T14 is null at high occupancy) and we save 16 loop regs.
    int   nidx_pf = nei[(size_t)n0 * 32 + gk];
    float wv      = 0.0f;
    if (tid < 32) wv = wei[(size_t)n0 * 32 + tid];

    for (int it = 0; it < 32; ++it) {
        const int node = n0 + it;
        if (node >= N) break;              // block-uniform
        const int   nidx = nidx_pf;
        const float wvc  = wv;
        if (it + 1 < 32 && node + 1 < N) {
            nidx_pf = nei[(size_t)(node + 1) * 32 + gk];
            if (tid < 32) wv = wei[(size_t)(node + 1) * 32 + tid];
        }

        // ---- stage: hst only (bf16 h*s, tiled+swizzled) + bias slots
        if (tid < 32)
            *(uint2*)&hst[hidx(12, tid) + 4] = make_uint2(pk2(wvc, 1.0f), 0u);
        {
            const float4* erow = (const float4*)(emb + (size_t)nidx * 100);
            const float4* srow = (const float4*)(s_vec + (size_t)node * 100);
            float4 hA = erow[gj],      sA = srow[gj];
            float4 hB = erow[gj + 8],  sB = srow[gj + 8];
            float4 hC = erow[gj + 16], sC = srow[gj + 16];
            float4 hD, sD;
            if (t24) { hD = erow[24]; sD = srow[24]; }
            #define ST_C4(c4, h4, s4) \
                *(uint2*)&hst[hidx((c4) >> 1, gk) + ((c4) & 1) * 4] = \
                    make_uint2(pk2(h4.x * s4.x, h4.y * s4.y), pk2(h4.z * s4.z, h4.w * s4.w));
            ST_C4(gj,      hA, sA)
            ST_C4(gj + 8,  hB, sB)
            ST_C4(gj + 16, hC, sC)
            if (t24) { ST_C4(24, hD, sD) }
            #undef ST_C4
        }
        // ---- W1 A-frags, first half (peak 16 regs in flight; latency shadowed
        // by the erow drain at B1 anyway)
        asm volatile("" : "+v"(w1off));
        const unsigned short* w1p = W1t + w1off;
        bf16x8 af0 = *(const bf16x8*)(w1p);
        bf16x8 af1 = *(const bf16x8*)(w1p + 16);
        bf16x8 af2 = *(const bf16x8*)(w1p + 32);
        bf16x8 af3 = *(const bf16x8*)(w1p + 48);
        __syncthreads();   // B1

        // ---- TRANSPOSED score matmul: C[row = n (per reg)][col = k (lane&31)]
        #define HF(ks) (*(const bf16x8*)&hst[hidx(2 * (ks) + hi, col)])
        f32x16 acc;
        #pragma unroll
        for (int r = 0; r < 16; ++r) acc[r] = 0.0f;
        acc = __builtin_amdgcn_mfma_f32_32x32x16_bf16(af0, HF(0), acc, 0, 0, 0);
        acc = __builtin_amdgcn_mfma_f32_32x32x16_bf16(af1, HF(1), acc, 0, 0, 0);
        acc = __builtin_amdgcn_mfma_f32_32x32x16_bf16(af2, HF(2), acc, 0, 0, 0);
        acc = __builtin_amdgcn_mfma_f32_32x32x16_bf16(af3, HF(3), acc, 0, 0, 0);
        // second half behind a scheduling fence so the loads can't hoist and
        // re-create the 28-reg window
        __builtin_amdgcn_sched_barrier(0);
        {
            bf16x8 af4 = *(const bf16x8*)(w1p + 64);
            bf16x8 af5 = *(const bf16x8*)(w1p + 80);
            bf16x8 af6 = *(const bf16x8*)(w1p + 96);
            acc = __builtin_amdgcn_mfma_f32_32x32x16_bf16(af4, HF(4), acc, 0, 0, 0);
            acc = __builtin_amdgcn_mfma_f32_32x32x16_bf16(af5, HF(5), acc, 0, 0, 0);
            acc = __builtin_amdgcn_mfma_f32_32x32x16_bf16(af6, HF(6), acc, 0, 0, 0);
        }
        #undef HF

        // ---- epilogue: sum_n tanh(S)*q1 in-lane over 16 regs + one permlane32
        asm volatile("" : "+v"(q1off));
        const float* qp = q1pad + q1off;
        float part = 0.0f;
        #pragma unroll
        for (int m = 0; m < 4; ++m) {
            float4 jq = *(const float4*)(qp + 8 * m);   // padded -> no guard
            part = fmaf(fast_tanh(acc[4 * m + 0]), jq.x, part);
            part = fmaf(fast_tanh(acc[4 * m + 1]), jq.y, part);
            part = fmaf(fast_tanh(acc[4 * m + 2]), jq.z, part);
            part = fmaf(fast_tanh(acc[4 * m + 3]), jq.w, part);
        }
        part = pl32_add(part);
        if (lane < 32) spart[w * 32 + lane] = part;   // per-wave 32-n partial, k=lane
        __syncthreads();   // B2

        // ---- softmax over k, redundantly per wave (DPP/permlane, VALU pipe)
        float attk;
        {
            float s = spart[col] + spart[32 + col] + spart[64 + col] + spart[96 + col];
            float mx = s;
            mx = dpp_max<0x121>(mx);
            mx = dpp_max<0x122>(mx);
            mx = dpp_max<0x124>(mx);
            mx = dpp_max<0x128>(mx);
            mx = pl16_max(mx);
            float e = __expf(s - mx);
            float den = e;
            den = dpp_add<0x121>(den);
            den = dpp_add<0x122>(den);
            den = dpp_add<0x124>(den);
            den = dpp_add<0x128>(den);
            den = pl16_add(den);
            float attv = e * __builtin_amdgcn_rcpf(den);
            attk = __shfl(attv, w * 8 + (lane >> 3));   // att for my k-row
        }

        // ---- msg partials from hst (= h*s; /s happens at the final reduce).
        // Sequential m1 then m2 halves the live-value peak. Full in-wave
        // k-butterfly (k^1 dpp ror:8, k^2 permlane16, k^4 permlane32).
        {
            const int oct  = lane & 7;
            const int krow = w * 8 + (lane >> 3);
            const float a  = attk;
            float* p = &part2[w * 100];
            #define UNP2(u, d0, d1) { d0 = __builtin_bit_cast(float, (u) << 16); \
                                      d1 = __builtin_bit_cast(float, (u) & 0xffff0000u); }
            {
                uint4 r1 = *(const uint4*)&hst[hidx(oct, krow)];
                float m1[8];
                { float t0,t1; UNP2(r1.x,t0,t1); m1[0]=a*t0; m1[1]=a*t1; }
                { float t0,t1; UNP2(r1.y,t0,t1); m1[2]=a*t0; m1[3]=a*t1; }
                { float t0,t1; UNP2(r1.z,t0,t1); m1[4]=a*t0; m1[5]=a*t1; }
                { float t0,t1; UNP2(r1.w,t0,t1); m1[6]=a*t0; m1[7]=a*t1; }
                #pragma unroll
                for (int j = 0; j < 8; ++j) {
                    m1[j] = dpp_add<0x128>(m1[j]);
                    m1[j] = pl16_add(m1[j]);
                    m1[j] = pl32_add(m1[j]);
                }
                if ((lane >> 3) == 0) {
                    *(float4*)&p[oct * 8]     = make_float4(m1[0], m1[1], m1[2], m1[3]);
                    *(float4*)&p[oct * 8 + 4] = make_float4(m1[4], m1[5], m1[6], m1[7]);
                }
            }
            {
                const int oct2 = (oct < 5) ? oct : 4;   // clamped dup, masked at write
                uint4 r2 = *(const uint4*)&hst[hidx(8 + oct2, krow)];
                float m2[8];
                { float t0,t1; UNP2(r2.x,t0,t1); m2[0]=a*t0; m2[1]=a*t1; }
                { float t0,t1; UNP2(r2.y,t0,t1); m2[2]=a*t0; m2[3]=a*t1; }
                { float t0,t1; UNP2(r2.z,t0,t1); m2[4]=a*t0; m2[5]=a*t1; }
                { float t0,t1; UNP2(r2.w,t0,t1); m2[6]=a*t0; m2[7]=a*t1; }
                #pragma unroll
                for (int j = 0; j < 8; ++j) {
                    m2[j] = dpp_add<0x128>(m2[j]);
                    m2[j] = pl16_add(m2[j]);
                    m2[j] = pl32_add(m2[j]);
                }
                if ((lane >> 3) == 0) {
                    if (oct < 5) *(float4*)&p[64 + oct * 8]     = make_float4(m2[0], m2[1], m2[2], m2[3]);
                    if (oct < 4) *(float4*)&p[64 + oct * 8 + 4] = make_float4(m2[4], m2[5], m2[6], m2[7]);
                }
            }
            #undef UNP2
        }
        __syncthreads();   // B4

        // ---- reduce 4 per-wave partials, recover h via /s_vec -> msg_s (bf16)
        if (w < 2) {
            int d = w * 64 + lane;
            if (d < 100) {
                float s  = part2[d] + part2[100 + d] + part2[200 + d] + part2[300 + d];
                float sv = s_vec[(size_t)node * 100 + d];
                float mv = (sv != 0.0f) ? s * __builtin_amdgcn_rcpf(sv) : 0.0f;
                msg_s[it * HP + d] = f2bf(mv);
            }
        }
    }

    // ================= layer phase: x = relu([x,msg]@W2+b2) twice =================
    // x rows reuse the hst region, UNswizzled [32][HP] layout (all attn reads of
    // hst completed before the final B4; msg-reduce touches only part2/s_vec/msg_s).
    unsigned short* x_s = hst;
    const float b2v = nok ? b2[n] : 0.0f;
    {
        int row = n0 + gk;
        int rc = row < N ? row : N - 1;
        const float4* xr = (const float4*)(emb + (size_t)nodes[rc] * 100);
        float4 x0 = xr[gj], x1 = xr[gj + 8], x2 = xr[gj + 16];
        float4 x3;
        if (t24) x3 = xr[24];
        *(uint2*)&x_s[gk * HP + gj * 4]        = make_uint2(pk2(x0.x, x0.y), pk2(x0.z, x0.w));
        *(uint2*)&x_s[gk * HP + (gj + 8) * 4]  = make_uint2(pk2(x1.x, x1.y), pk2(x1.z, x1.w));
        *(uint2*)&x_s[gk * HP + (gj + 16) * 4] = make_uint2(pk2(x2.x, x2.y), pk2(x2.z, x2.w));
        if (t24)
            *(uint2*)&x_s[gk * HP + 96]        = make_uint2(pk2(x3.x, x3.y), pk2(x3.z, x3.w));
    }
    if (tid < 32) *(uint2*)&x_s[tid * HP + 100] = make_uint2(0, 0);   // zero pad
    __syncthreads();   // B_L1

    // A-frag address: k' blocks 0..12 -> x_s, 13..25 -> msg_s (ks=6 splits on hi)
    #define AFRAG(ks) (*(const bf16x8*)( \
        (ks) < 6  ? &x_s[col * HP + (ks) * 16 + hi * 8] : \
        (ks) == 6 ? (hi ? &msg_s[col * HP] : &x_s[col * HP + 96]) : \
                    &msg_s[col * HP + (ks) * 16 + hi * 8 - 104]))
    #define BFRAG(ks) (*(const bf16x8*)(W2t + n * 208 + (ks) * 16 + hi * 8))

    f32x16 acc;
    #pragma unroll
    for (int r = 0; r < 16; ++r) acc[r] = b2v;
    #pragma unroll 2
    for (int ks = 0; ks < 13; ++ks)
        acc = __builtin_amdgcn_mfma_f32_32x32x16_bf16(AFRAG(ks), BFRAG(ks), acc, 0, 0, 0);
    __syncthreads();   // B_L2: pass-1 reads done
    if (nok) {
        #pragma unroll
        for (int r = 0; r < 16; ++r) {
            int m = (r & 3) + 8 * (r >> 2) + 4 * hi;
            x_s[m * HP + n] = f2bf(fmaxf(acc[r], 0.0f));
        }
    }
    __syncthreads();   // B_L3

    f32x16 acc2;
    #pragma unroll
    for (int r = 0; r < 16; ++r) acc2[r] = b2v;
    #pragma unroll 2
    for (int ks = 0; ks < 13; ++ks)
        acc2 = __builtin_amdgcn_mfma_f32_32x32x16_bf16(AFRAG(ks), BFRAG(ks), acc2, 0, 0, 0);
    #undef AFRAG
    #undef BFRAG
    if (nok) {
        #pragma unroll
        for (int r = 0; r < 16; ++r) {
            int m = (r & 3) + 8 * (r >> 2) + 4 * hi;
            int row = n0 + m;
            if (row < N) out[(size_t)row * 100 + n] = fmaxf(acc2[r], 0.0f);
        }
    }
}

// ---------------- launch ----------------
extern "C" void kernel_launch(void* const* d_in, const int* in_sizes, int n_in,
                              void* d_out, int out_size, void* d_ws, size_t ws_size,
                              hipStream_t stream) {
    const int*   nodes = (const int*)d_in[0];
    const int*   nei   = (const int*)d_in[1];
    const float* wei   = (const float*)d_in[2];
    const float* s_vec = (const float*)d_in[3];
    const float* emb   = (const float*)d_in[4];
    const float* W1    = (const float*)d_in[5];
    const float* b1    = (const float*)d_in[6];
    const float* q1    = (const float*)d_in[7];
    const float* W2    = (const float*)d_in[8];
    const float* b2    = (const float*)d_in[9];
    float* out = (float*)d_out;
    const int N = in_sizes[0];

    unsigned short* W1t = (unsigned short*)d_ws;       // 128*128*2 = 32 KB
    unsigned short* W2t = W1t + 128 * 128;             // 128*208*2 = 52 KB
    float* q1pad = (float*)(W2t + 128 * 208);          // 128*4 = 512 B

    prep_kernel<<<168, 256, 0, stream>>>(W1, b1, W2, q1, W1t, W2t, q1pad);
    const int gB = (N + 31) / 32;
    fused_kernel<<<gB, 256, 0, stream>>>(nodes, nei, wei, s_vec, emb,
                                         W1t, W2t, q1pad, b2, out, N);
}